// Round 1
// baseline (211.144 us; speedup 1.0000x reference)
//
#include <hip/hip_runtime.h>

// Dynamic voxelization: per-point voxel coords (z,y,x) int32, -1 if out of range.
// VOXEL_SIZE = (0.05, 0.05, 0.1); PC_RANGE = (0,-40,-3, 70.4,40,1); GRID = (1408,1600,40)

constexpr float VX = 0.05f, VY = 0.05f, VZ = 0.1f;
constexpr float X0 = 0.0f, Y0 = -40.0f, Z0 = -3.0f;
constexpr int GX = 1408, GY = 1600, GZ = 40;

__global__ __launch_bounds__(256)
void voxelize_kernel(const float4* __restrict__ pts, int* __restrict__ out, int n) {
    const int t = blockIdx.x * blockDim.x + threadIdx.x;
    const int i = t * 4;
    if (i >= n) return;

    if (i + 4 <= n) {
        int4 zc, yc, xc;
#pragma unroll
        for (int j = 0; j < 4; ++j) {
            const float4 p = pts[i + j];
            // Match reference numerics exactly: IEEE f32 division + floorf.
            int cx = (int)floorf((p.x - X0) / VX);
            int cy = (int)floorf((p.y - Y0) / VY);
            int cz = (int)floorf((p.z - Z0) / VZ);
            const bool valid = (cx >= 0) & (cx < GX) &
                               (cy >= 0) & (cy < GY) &
                               (cz >= 0) & (cz < GZ);
            cx = valid ? cx : -1;
            cy = valid ? cy : -1;
            cz = valid ? cz : -1;
            ((int*)&zc)[j] = cz;
            ((int*)&yc)[j] = cy;
            ((int*)&xc)[j] = cx;
        }
        // Output rows: (z, y, x), each row length n. i is a multiple of 4 and n
        // is a multiple of 4 in practice -> 16B-aligned int4 stores.
        *(int4*)(out + i)         = zc;
        *(int4*)(out + n + i)     = yc;
        *(int4*)(out + 2 * n + i) = xc;
    } else {
        // Scalar tail (not hit for N = 8M, kept for generality).
        for (int k = i; k < n; ++k) {
            const float4 p = pts[k];
            int cx = (int)floorf((p.x - X0) / VX);
            int cy = (int)floorf((p.y - Y0) / VY);
            int cz = (int)floorf((p.z - Z0) / VZ);
            const bool valid = (cx >= 0) & (cx < GX) &
                               (cy >= 0) & (cy < GY) &
                               (cz >= 0) & (cz < GZ);
            out[k]         = valid ? cz : -1;
            out[n + k]     = valid ? cy : -1;
            out[2 * n + k] = valid ? cx : -1;
        }
    }
}

extern "C" void kernel_launch(void* const* d_in, const int* in_sizes, int n_in,
                              void* d_out, int out_size, void* d_ws, size_t ws_size,
                              hipStream_t stream) {
    const float4* pts = (const float4*)d_in[0];
    int* out = (int*)d_out;
    const int n = in_sizes[0] / 4;  // points, each 4 floats

    const int pts_per_thread = 4;
    const int threads = 256;
    const int work_items = (n + pts_per_thread - 1) / pts_per_thread;
    const int blocks = (work_items + threads - 1) / threads;

    voxelize_kernel<<<blocks, threads, 0, stream>>>(pts, out, n);
}

// Round 3
// 197.509 us; speedup vs baseline: 1.0690x; 1.0690x over previous
//
#include <hip/hip_runtime.h>

// Dynamic voxelization: per-point voxel coords (z,y,x) int32, -1 if out of range.
// VOXEL_SIZE = (0.05, 0.05, 0.1); PC_RANGE = (0,-40,-3, 70.4,40,1); GRID = (1408,1600,40)
//
// Layout: thread t, iter j handles point blk*(TPB*PPT) + j*TPB + t.
//  - loads:  16 B/lane, lane-contiguous -> 1 KB per wave-instruction
//  - stores:  4 B/lane, lane-contiguous -> 256 B per wave-instruction
// Both fully coalesced; nontemporal (read-once / write-once streaming).

constexpr float VX = 0.05f, VY = 0.05f, VZ = 0.1f;
constexpr float X0 = 0.0f, Y0 = -40.0f, Z0 = -3.0f;
constexpr int GX = 1408, GY = 1600, GZ = 40;

constexpr int TPB = 256;  // threads per block
constexpr int PPT = 4;    // points per thread

// Native clang vector type: __builtin_nontemporal_load requires a pointer to
// int/float/pointer or a native vector thereof (HIP's float4 struct is invalid).
typedef float vfloat4 __attribute__((ext_vector_type(4)));

__global__ __launch_bounds__(TPB)
void voxelize_kernel(const vfloat4* __restrict__ pts, int* __restrict__ out, int n) {
    const int base = blockIdx.x * (TPB * PPT) + threadIdx.x;

#pragma unroll
    for (int j = 0; j < PPT; ++j) {
        const int p = base + j * TPB;
        if (p < n) {
            const vfloat4 q = __builtin_nontemporal_load(pts + p);
            // Match reference numerics: IEEE f32 division + floorf.
            int cx = (int)floorf((q.x - X0) / VX);
            int cy = (int)floorf((q.y - Y0) / VY);
            int cz = (int)floorf((q.z - Z0) / VZ);
            const bool valid = (cx >= 0) & (cx < GX) &
                               (cy >= 0) & (cy < GY) &
                               (cz >= 0) & (cz < GZ);
            cz = valid ? cz : -1;
            cy = valid ? cy : -1;
            cx = valid ? cx : -1;
            // Output rows: (z, y, x), each of length n.
            __builtin_nontemporal_store(cz, out + p);
            __builtin_nontemporal_store(cy, out + n + p);
            __builtin_nontemporal_store(cx, out + 2 * n + p);
        }
    }
}

extern "C" void kernel_launch(void* const* d_in, const int* in_sizes, int n_in,
                              void* d_out, int out_size, void* d_ws, size_t ws_size,
                              hipStream_t stream) {
    const vfloat4* pts = (const vfloat4*)d_in[0];
    int* out = (int*)d_out;
    const int n = in_sizes[0] / 4;  // points, each 4 floats

    const int per_block = TPB * PPT;
    const int blocks = (n + per_block - 1) / per_block;

    voxelize_kernel<<<blocks, TPB, 0, stream>>>(pts, out, n);
}